// Round 2
// baseline (3050.413 us; speedup 1.0000x reference)
//
#include <hip/hip_runtime.h>
#include <hip/hip_bf16.h>

#define L 2048
#define D 2048
#define NH 32
#define NKV 8
#define HD 64
#define REP 4

// ---------------------------------------------------------------------------
// Generic tiled GEMM: C(MxN) = A(MxK) @ B(KxN), all fp32 row-major, fp32 acc.
// 64x64 block tile, 16 K-slice, 256 threads, 4x4 micro-tile per thread.
// ---------------------------------------------------------------------------
__global__ __launch_bounds__(256) void gemm_f32_kernel(
    const float* __restrict__ A, const float* __restrict__ B, float* __restrict__ C,
    int M, int N, int K)
{
    __shared__ float As[64][17];   // [m][k], +1 pad
    __shared__ float Bs[16][64];   // [k][n]
    const int tid = threadIdx.x;
    const int tx = tid & 15, ty = tid >> 4;
    const int m0 = blockIdx.y * 64, n0 = blockIdx.x * 64;
    float acc[4][4] = {};

    for (int kt = 0; kt < K; kt += 16) {
#pragma unroll
        for (int i = 0; i < 4; ++i) {
            int idx = tid + 256 * i;
            int r = idx >> 4, kk = idx & 15;
            As[r][kk] = A[(size_t)(m0 + r) * K + kt + kk];
        }
#pragma unroll
        for (int i = 0; i < 4; ++i) {
            int idx = tid + 256 * i;
            int r = idx >> 6, cc = idx & 63;
            Bs[r][cc] = B[(size_t)(kt + r) * N + n0 + cc];
        }
        __syncthreads();
#pragma unroll
        for (int kk = 0; kk < 16; ++kk) {
            float a0 = As[ty][kk], a1 = As[ty + 16][kk];
            float a2 = As[ty + 32][kk], a3 = As[ty + 48][kk];
            float b0 = Bs[kk][tx], b1 = Bs[kk][tx + 16];
            float b2 = Bs[kk][tx + 32], b3 = Bs[kk][tx + 48];
            acc[0][0] += a0 * b0; acc[0][1] += a0 * b1; acc[0][2] += a0 * b2; acc[0][3] += a0 * b3;
            acc[1][0] += a1 * b0; acc[1][1] += a1 * b1; acc[1][2] += a1 * b2; acc[1][3] += a1 * b3;
            acc[2][0] += a2 * b0; acc[2][1] += a2 * b1; acc[2][2] += a2 * b2; acc[2][3] += a2 * b3;
            acc[3][0] += a3 * b0; acc[3][1] += a3 * b1; acc[3][2] += a3 * b2; acc[3][3] += a3 * b3;
        }
        __syncthreads();
    }
#pragma unroll
    for (int i = 0; i < 4; ++i)
#pragma unroll
        for (int j = 0; j < 4; ++j)
            C[(size_t)(m0 + ty + 16 * i) * N + n0 + tx + 16 * j] = acc[i][j];
}

// ---------------------------------------------------------------------------
// RoPE applied in-place to q (L, NH, HD) and k (L, NKV, HD). One thread per
// (row, head, pair). cos/sin fp32 (L, HD/2). Pairs are interleaved (even,odd).
// ---------------------------------------------------------------------------
__global__ void rope_kernel(float* __restrict__ q, float* __restrict__ k,
                            const float* __restrict__ cosb, const float* __restrict__ sinb)
{
    int idx = blockIdx.x * 256 + threadIdx.x;
    const int TQ = L * NH * (HD / 2);
    const int TK = L * NKV * (HD / 2);
    float* p; int row, i;
    if (idx < TQ) {
        i = idx & 31; int h = (idx >> 5) & (NH - 1); row = idx >> 10;
        p = q + (size_t)row * (NH * HD) + h * HD + 2 * i;
    } else if (idx < TQ + TK) {
        int j = idx - TQ;
        i = j & 31; int h = (j >> 5) & (NKV - 1); row = j >> 8;
        p = k + (size_t)row * (NKV * HD) + h * HD + 2 * i;
    } else {
        return;
    }
    float c = cosb[row * 32 + i];
    float s = sinb[row * 32 + i];
    float xr = p[0];
    float xi = p[1];
    p[0] = xr * c - xi * s;
    p[1] = xr * s + xi * c;
}

// ---------------------------------------------------------------------------
// Flash-style causal attention. Block = (head h, 4 consecutive q rows).
// 4 waves; wave w owns q-row q0+w. 64-key chunks staged in LDS.
// GQA: head h reads kv-head h/REP. Mask input unused: causal-skip with
// exp underflow to 0 is bit-equivalent to the -1e9 additive mask path.
// K stored stride-68 (16B-aligned rows, conflict-optimal float4 reads);
// V stored stride-65 (conflict-free column reads).
// ---------------------------------------------------------------------------
__global__ __launch_bounds__(256) void attn_kernel(
    const float* __restrict__ qb, const float* __restrict__ kb,
    const float* __restrict__ vb, float* __restrict__ ob)
{
    __shared__ float Ks[64][68];
    __shared__ float Vs[64][65];
    __shared__ float qs[4][64];
    __shared__ float ps[4][64];

    const int h = blockIdx.x;
    const int q0 = blockIdx.y * 4;
    const int g = h >> 2;            // kv head (REP = 4)
    const int tid = threadIdx.x;
    const int w = tid >> 6, lane = tid & 63;
    const int qr = q0 + w;

    qs[w][lane] = qb[((size_t)qr * NH + h) * HD + lane];

    float m_run = -INFINITY, l_run = 0.0f, o_run = 0.0f;
    const int nch = ((q0 + 3) >> 6) + 1;   // chunks of 64 keys, causal bound

    for (int c = 0; c < nch; ++c) {
        const int j0 = c * 64;
        __syncthreads();   // previous accum done (also covers qs preload)
#pragma unroll
        for (int i = 0; i < 16; ++i) {
            int idx = tid + 256 * i;
            int r = idx >> 6, d = idx & 63;
            size_t gaddr = ((size_t)(j0 + r) * NKV + g) * HD + d;
            Ks[r][d] = kb[gaddr];
            Vs[r][d] = vb[gaddr];
        }
        __syncthreads();

        const int j = j0 + lane;
        float s = -INFINITY;
        if (j <= qr) {
            float a = 0.0f;
            const float4* kr = (const float4*)&Ks[lane][0];
            const float4* qv = (const float4*)&qs[w][0];
#pragma unroll
            for (int d4 = 0; d4 < 16; ++d4) {
                float4 kk = kr[d4]; float4 qq = qv[d4];
                a += qq.x * kk.x + qq.y * kk.y + qq.z * kk.z + qq.w * kk.w;
            }
            s = a * 0.125f;      // 1/sqrt(64)
        }
        float mc = s;
#pragma unroll
        for (int off = 32; off; off >>= 1) mc = fmaxf(mc, __shfl_xor(mc, off));
        float m_new = fmaxf(m_run, mc);
        float alpha = __expf(m_run - m_new);   // exp(-inf) = 0 on first chunk
        float p = (j <= qr) ? __expf(s - m_new) : 0.0f;
        float pl = p;
#pragma unroll
        for (int off = 32; off; off >>= 1) pl += __shfl_xor(pl, off);
        l_run = l_run * alpha + pl;
        m_run = m_new;
        ps[w][lane] = p;
        // ps written and read by the same wave — no barrier needed in between

        float a = o_run * alpha;
        const float4* pv = (const float4*)&ps[w][0];
#pragma unroll
        for (int j4 = 0; j4 < 16; ++j4) {
            float4 pp = pv[j4];
            a += pp.x * Vs[4 * j4 + 0][lane];
            a += pp.y * Vs[4 * j4 + 1][lane];
            a += pp.z * Vs[4 * j4 + 2][lane];
            a += pp.w * Vs[4 * j4 + 3][lane];
        }
        o_run = a;
    }
    ob[(size_t)qr * (NH * HD) + h * HD + lane] = o_run / l_run;
}

// ---------------------------------------------------------------------------
extern "C" void kernel_launch(void* const* d_in, const int* in_sizes, int n_in,
                              void* d_out, int out_size, void* d_ws, size_t ws_size,
                              hipStream_t stream)
{
    const float* x  = (const float*)d_in[0];
    const float* wq = (const float*)d_in[1];
    const float* wk = (const float*)d_in[2];
    const float* wv = (const float*)d_in[3];
    const float* wo = (const float*)d_in[4];
    const float* fc = (const float*)d_in[5];
    const float* fs = (const float*)d_in[6];
    // d_in[7] = mask: unused (causal mask applied analytically)
    float* out = (float*)d_out;

    // Workspace layout (fp32): q (L*2048) | k (L*512) | v (L*512) | attn_out (L*2048)
    float* q_ws = (float*)d_ws;
    float* k_ws = q_ws + (size_t)L * (NH * HD);
    float* v_ws = k_ws + (size_t)L * (NKV * HD);
    float* a_ws = v_ws + (size_t)L * (NKV * HD);

    gemm_f32_kernel<<<dim3((NH * HD) / 64, L / 64), 256, 0, stream>>>(x, wq, q_ws, L, NH * HD, D);
    gemm_f32_kernel<<<dim3((NKV * HD) / 64, L / 64), 256, 0, stream>>>(x, wk, k_ws, L, NKV * HD, D);
    gemm_f32_kernel<<<dim3((NKV * HD) / 64, L / 64), 256, 0, stream>>>(x, wv, v_ws, L, NKV * HD, D);

    const int total_pairs = L * NH * (HD / 2) + L * NKV * (HD / 2);
    rope_kernel<<<(total_pairs + 255) / 256, 256, 0, stream>>>(q_ws, k_ws, fc, fs);

    attn_kernel<<<dim3(NH, L / 4), 256, 0, stream>>>(q_ws, k_ws, v_ws, a_ws);

    gemm_f32_kernel<<<dim3(D / 64, L / 64), 256, 0, stream>>>(a_ws, wo, out, L, D, NH * HD);
}

// Round 3
// 2313.485 us; speedup vs baseline: 1.3185x; 1.3185x over previous
//
#include <hip/hip_runtime.h>
#include <hip/hip_bf16.h>

#define L 2048
#define D 2048
#define NH 32
#define NKV 8
#define HD 64

typedef unsigned short u16;
typedef __attribute__((ext_vector_type(8))) short bf16x8;   // 8 bf16 in 4 VGPRs
typedef __attribute__((ext_vector_type(4))) float f32x4;

__device__ __forceinline__ u16 f2bf(float x) {
    __hip_bfloat16 b = __float2bfloat16(x);
    return *reinterpret_cast<u16*>(&b);
}

// ---------------------------------------------------------------------------
// Elementwise fp32 -> bf16 cast (x matrix), float4-vectorized.
// ---------------------------------------------------------------------------
__global__ void cast_x_kernel(const float* __restrict__ in, u16* __restrict__ out, int n4)
{
    int i = blockIdx.x * 256 + threadIdx.x;
    if (i < n4) {
        float4 v = ((const float4*)in)[i];
        ushort4 o;
        o.x = f2bf(v.x); o.y = f2bf(v.y); o.z = f2bf(v.z); o.w = f2bf(v.w);
        ((ushort4*)out)[i] = o;
    }
}

// ---------------------------------------------------------------------------
// Cast + transpose: in fp32 [R][C] row-major -> out bf16 [C][R] row-major.
// 32x32 LDS tile (pad 33), block 256 = 32x8.
// ---------------------------------------------------------------------------
__global__ __launch_bounds__(256) void cast_transpose_kernel(
    const float* __restrict__ in, u16* __restrict__ out, int R, int C)
{
    __shared__ float tile[32][33];
    const int tx = threadIdx.x & 31, ty = threadIdx.x >> 5;
    const int r0 = blockIdx.y * 32, c0 = blockIdx.x * 32;
#pragma unroll
    for (int i = 0; i < 32; i += 8)
        tile[ty + i][tx] = in[(size_t)(r0 + ty + i) * C + c0 + tx];
    __syncthreads();
#pragma unroll
    for (int i = 0; i < 32; i += 8)
        out[(size_t)(c0 + ty + i) * R + r0 + tx] = f2bf(tile[tx][ty + i]);
}

// ---------------------------------------------------------------------------
// MFMA bf16 GEMM: C(MxN fp32) = A(MxK bf16, row-major) @ Bt(NxK bf16,
// row-major = B transposed). 128x128 tile, BK=32, 4 waves in 2x2, each wave
// 64x64 = 4x4 mfma_f32_16x16x32_bf16 tiles.
// A-frag: A[m=lane&15][k=(lane>>4)*8+j]; B-frag symmetric from Bt.
// C/D: row=(lane>>4)*4+reg, col=lane&15  [verified layouts, guide §3].
// ---------------------------------------------------------------------------
__global__ __launch_bounds__(256) void gemm_mfma_kernel(
    const u16* __restrict__ A, const u16* __restrict__ Bt, float* __restrict__ C,
    int M, int N, int K)
{
    __shared__ __align__(16) u16 As[128 * 32];
    __shared__ __align__(16) u16 Bs[128 * 32];
    const int tid = threadIdx.x;
    const int w = tid >> 6, lane = tid & 63;
    const int m0 = blockIdx.y * 128, n0 = blockIdx.x * 128;
    const int wm = (w >> 1) * 64, wn = (w & 1) * 64;
    const int m15 = lane & 15, q8 = (lane >> 4) * 8;

    f32x4 acc[4][4];
#pragma unroll
    for (int i = 0; i < 4; ++i)
#pragma unroll
        for (int j = 0; j < 4; ++j)
            acc[i][j] = (f32x4){0.f, 0.f, 0.f, 0.f};

    for (int kt = 0; kt < K; kt += 32) {
        __syncthreads();
#pragma unroll
        for (int i = 0; i < 2; ++i) {
            int idx = tid + 256 * i;              // 0..511
            int r = idx >> 2, c8 = (idx & 3) * 8;
            *(uint4*)&As[r * 32 + c8] = *(const uint4*)&A[(size_t)(m0 + r) * K + kt + c8];
            *(uint4*)&Bs[r * 32 + c8] = *(const uint4*)&Bt[(size_t)(n0 + r) * K + kt + c8];
        }
        __syncthreads();
        bf16x8 af[4], bfr[4];
#pragma unroll
        for (int t = 0; t < 4; ++t) {
            af[t]  = *(const bf16x8*)&As[(wm + t * 16 + m15) * 32 + q8];
            bfr[t] = *(const bf16x8*)&Bs[(wn + t * 16 + m15) * 32 + q8];
        }
#pragma unroll
        for (int i = 0; i < 4; ++i)
#pragma unroll
            for (int j = 0; j < 4; ++j)
                acc[i][j] = __builtin_amdgcn_mfma_f32_16x16x32_bf16(af[i], bfr[j], acc[i][j], 0, 0, 0);
    }
#pragma unroll
    for (int i = 0; i < 4; ++i)
#pragma unroll
        for (int j = 0; j < 4; ++j)
#pragma unroll
            for (int r = 0; r < 4; ++r)
                C[(size_t)(m0 + wm + i * 16 + (lane >> 4) * 4 + r) * N + n0 + wn + j * 16 + m15] = acc[i][j][r];
}

// ---------------------------------------------------------------------------
// RoPE in-place: q fp32 (L, NH, HD); k = first half of each kv row,
// kv fp32 (L, 2*NKV*HD) with K at cols [g*64, +64), V at [512 + g*64, +64).
// ---------------------------------------------------------------------------
__global__ void rope_kernel(float* __restrict__ q, float* __restrict__ kv,
                            const float* __restrict__ cosb, const float* __restrict__ sinb)
{
    int idx = blockIdx.x * 256 + threadIdx.x;
    const int TQ = L * NH * (HD / 2);
    const int TK = L * NKV * (HD / 2);
    float* p; int row, i;
    if (idx < TQ) {
        i = idx & 31; int hh = (idx >> 5) & (NH - 1); row = idx >> 10;
        p = q + (size_t)row * (NH * HD) + hh * HD + 2 * i;
    } else if (idx < TQ + TK) {
        int j = idx - TQ;
        i = j & 31; int hh = (j >> 5) & (NKV - 1); row = j >> 8;
        p = kv + (size_t)row * (NKV * HD * 2) + hh * HD + 2 * i;
    } else {
        return;
    }
    float cc = cosb[row * 32 + i], ss = sinb[row * 32 + i];
    float xr = p[0], xi = p[1];
    p[0] = xr * cc - xi * ss;
    p[1] = xr * ss + xi * cc;
}

// ---------------------------------------------------------------------------
// Causal GQA attention, no-LDS design. Lane-pair per q-row: even lane dims
// 0-31, odd lane dims 32-63. Wave = 32 q-rows (one 32-row group). Q, O, S
// all registers; K/V read from global with wave-broadcast float4 loads
// (2 distinct 16B addresses per instr; kv is 8MB -> L2-served).
// Causal balance: wave handles group g then group 63-g ((g+1)+(64-g)=const).
// Output written as bf16 directly (input to the out-projection GEMM).
// ---------------------------------------------------------------------------
__global__ __launch_bounds__(256) void attn_kernel(
    const float* __restrict__ qb, const float* __restrict__ kvb, u16* __restrict__ ob)
{
    const int h = blockIdx.x;
    const int gkv = h >> 2;                 // kv head (REP=4)
    const int w = threadIdx.x >> 6, lane = threadIdx.x & 63;
    const int g1 = blockIdx.y * 4 + w;      // 0..31

#pragma unroll 1
    for (int ph = 0; ph < 2; ++ph) {
        const int grp = ph ? (63 - g1) : g1;        // row group, rows grp*32..+31
        const int r = grp * 32 + (lane >> 1);
        const int dh = (lane & 1) * 32;             // d-half
        const float4* qp = (const float4*)(qb + (size_t)r * (NH * HD) + h * HD + dh);
        float4 Q[8], O[8];
#pragma unroll
        for (int i = 0; i < 8; ++i) {
            Q[i] = qp[i];
            O[i] = make_float4(0.f, 0.f, 0.f, 0.f);
        }
        float m_run = -1e30f, l_run = 0.0f;
        const float* Kb = kvb + gkv * HD + dh;
        const float* Vb = Kb + NKV * HD;            // +512
        const int nch = grp + 1;

        for (int c = 0; c < nch; ++c) {
            const int j0 = c * 32;
            float S[32];
#pragma unroll
            for (int j = 0; j < 32; ++j) {
                const float4* kp = (const float4*)(Kb + (size_t)(j0 + j) * (2 * NKV * HD));
                float a0 = 0.f, a1 = 0.f;
#pragma unroll
                for (int d = 0; d < 8; d += 2) {
                    float4 k0 = kp[d], k1 = kp[d + 1];
                    a0 += Q[d].x * k0.x + Q[d].y * k0.y + Q[d].z * k0.z + Q[d].w * k0.w;
                    a1 += Q[d + 1].x * k1.x + Q[d + 1].y * k1.y + Q[d + 1].z * k1.z + Q[d + 1].w * k1.w;
                }
                float a = a0 + a1;
                a += __shfl_xor(a, 1);              // combine d-halves within pair
                S[j] = (j0 + j <= r) ? a * 0.125f : -1e30f;
            }
            float mc = S[0];
#pragma unroll
            for (int j = 1; j < 32; ++j) mc = fmaxf(mc, S[j]);
            const float m_new = fmaxf(m_run, mc);
            const float alpha = __expf(m_run - m_new);
            float l = l_run * alpha;
#pragma unroll
            for (int j = 0; j < 32; ++j) { S[j] = __expf(S[j] - m_new); l += S[j]; }
            l_run = l; m_run = m_new;
#pragma unroll
            for (int i = 0; i < 8; ++i) {
                O[i].x *= alpha; O[i].y *= alpha; O[i].z *= alpha; O[i].w *= alpha;
            }
#pragma unroll
            for (int j = 0; j < 32; ++j) {
                const float4* vp = (const float4*)(Vb + (size_t)(j0 + j) * (2 * NKV * HD));
                const float p = S[j];
#pragma unroll
                for (int d = 0; d < 8; ++d) {
                    float4 v = vp[d];
                    O[d].x += p * v.x; O[d].y += p * v.y; O[d].z += p * v.z; O[d].w += p * v.w;
                }
            }
        }
        const float inv = 1.0f / l_run;
        u16* op = ob + (size_t)r * (NH * HD) + h * HD + dh;
#pragma unroll
        for (int i = 0; i < 8; ++i) {
            ushort4 o4;
            o4.x = f2bf(O[i].x * inv); o4.y = f2bf(O[i].y * inv);
            o4.z = f2bf(O[i].z * inv); o4.w = f2bf(O[i].w * inv);
            ((ushort4*)op)[i] = o4;
        }
    }
}

// ---------------------------------------------------------------------------
extern "C" void kernel_launch(void* const* d_in, const int* in_sizes, int n_in,
                              void* d_out, int out_size, void* d_ws, size_t ws_size,
                              hipStream_t stream)
{
    const float* x  = (const float*)d_in[0];
    const float* wq = (const float*)d_in[1];
    const float* wk = (const float*)d_in[2];
    const float* wv = (const float*)d_in[3];
    const float* wo = (const float*)d_in[4];
    const float* fc = (const float*)d_in[5];
    const float* fs = (const float*)d_in[6];
    // d_in[7] = mask: unused (causal handled analytically; -1e9 path == exp underflow)
    float* out = (float*)d_out;

    // Workspace (60 MB):
    // xb bf16[2048*2048] | wqT bf16[2048*2048] | wkvT bf16[1024*2048] |
    // woT bf16[2048*2048] | q_ws f32[2048*2048] | kv_ws f32[2048*1024] | ab bf16[2048*2048]
    u16*   xb    = (u16*)d_ws;
    u16*   wqT   = xb   + (size_t)2048 * 2048;
    u16*   wkvT  = wqT  + (size_t)2048 * 2048;
    u16*   woT   = wkvT + (size_t)1024 * 2048;
    float* q_ws  = (float*)(woT + (size_t)2048 * 2048);
    float* kv_ws = q_ws + (size_t)2048 * 2048;
    u16*   ab    = (u16*)(kv_ws + (size_t)2048 * 1024);

    cast_x_kernel<<<4096, 256, 0, stream>>>(x, xb, (2048 * 2048) / 4);
    cast_transpose_kernel<<<dim3(64, 64), 256, 0, stream>>>(wq, wqT, 2048, 2048);
    cast_transpose_kernel<<<dim3(16, 64), 256, 0, stream>>>(wk, wkvT, 2048, 512);
    cast_transpose_kernel<<<dim3(16, 64), 256, 0, stream>>>(wv, wkvT + (size_t)512 * 2048, 2048, 512);
    cast_transpose_kernel<<<dim3(64, 64), 256, 0, stream>>>(wo, woT, 2048, 2048);

    gemm_mfma_kernel<<<dim3(16, 16), 256, 0, stream>>>(xb, wqT, q_ws, 2048, 2048, 2048);
    gemm_mfma_kernel<<<dim3(8, 16), 256, 0, stream>>>(xb, wkvT, kv_ws, 2048, 1024, 2048);

    const int total_pairs = L * NH * (HD / 2) + L * NKV * (HD / 2);
    rope_kernel<<<(total_pairs + 255) / 256, 256, 0, stream>>>(q_ws, kv_ws, fc, fs);

    attn_kernel<<<dim3(NH, 8), 256, 0, stream>>>(q_ws, kv_ws, ab);

    gemm_mfma_kernel<<<dim3(16, 16), 256, 0, stream>>>(ab, woT, out, 2048, 2048, 2048);
}

// Round 4
// 346.144 us; speedup vs baseline: 8.8126x; 6.6836x over previous
//
#include <hip/hip_runtime.h>
#include <hip/hip_bf16.h>

#define L 2048
#define D 2048
#define NH 32
#define NKV 8
#define HD 64

typedef unsigned short u16;
typedef __attribute__((ext_vector_type(8))) short bf16x8;   // 8 bf16 in 4 VGPRs
typedef __attribute__((ext_vector_type(4))) float f32x4;

__device__ __forceinline__ u16 f2bf(float x) {
    __hip_bfloat16 b = __float2bfloat16(x);
    return *reinterpret_cast<u16*>(&b);
}

// ---------------------------------------------------------------------------
// Elementwise fp32 -> bf16 cast (x matrix), float4-vectorized.
// ---------------------------------------------------------------------------
__global__ void cast_x_kernel(const float* __restrict__ in, u16* __restrict__ out, int n4)
{
    int i = blockIdx.x * 256 + threadIdx.x;
    if (i < n4) {
        float4 v = ((const float4*)in)[i];
        ushort4 o;
        o.x = f2bf(v.x); o.y = f2bf(v.y); o.z = f2bf(v.z); o.w = f2bf(v.w);
        ((ushort4*)out)[i] = o;
    }
}

// ---------------------------------------------------------------------------
// Cast + transpose: out[c*ldo + r] = bf16(in[r*ldi + c]). 32x32 LDS tiles.
// ---------------------------------------------------------------------------
__global__ __launch_bounds__(256) void cast_transpose_kernel(
    const float* __restrict__ in, u16* __restrict__ out, int ldi, int ldo)
{
    __shared__ float tile[32][33];
    const int tx = threadIdx.x & 31, ty = threadIdx.x >> 5;
    const int r0 = blockIdx.y * 32, c0 = blockIdx.x * 32;
#pragma unroll
    for (int i = 0; i < 32; i += 8)
        tile[ty + i][tx] = in[(size_t)(r0 + ty + i) * ldi + c0 + tx];
    __syncthreads();
#pragma unroll
    for (int i = 0; i < 32; i += 8)
        out[(size_t)(c0 + ty + i) * ldo + r0 + tx] = f2bf(tile[tx][ty + i]);
}

// ---------------------------------------------------------------------------
// MFMA bf16 GEMM: C(MxN fp32) = A(MxK bf16 rm) @ Bt(NxK bf16 rm).
// 128x128 tile, BK=32, 4 waves 2x2, wave = 4x4 mfma_f32_16x16x32_bf16.
// ---------------------------------------------------------------------------
__global__ __launch_bounds__(256) void gemm_mfma_kernel(
    const u16* __restrict__ A, const u16* __restrict__ Bt, float* __restrict__ C,
    int M, int N, int K)
{
    __shared__ __align__(16) u16 As[128 * 32];
    __shared__ __align__(16) u16 Bs[128 * 32];
    const int tid = threadIdx.x;
    const int w = tid >> 6, lane = tid & 63;
    const int m0 = blockIdx.y * 128, n0 = blockIdx.x * 128;
    const int wm = (w >> 1) * 64, wn = (w & 1) * 64;
    const int m15 = lane & 15, q8 = (lane >> 4) * 8;

    f32x4 acc[4][4];
#pragma unroll
    for (int i = 0; i < 4; ++i)
#pragma unroll
        for (int j = 0; j < 4; ++j)
            acc[i][j] = (f32x4){0.f, 0.f, 0.f, 0.f};

    for (int kt = 0; kt < K; kt += 32) {
        __syncthreads();
#pragma unroll
        for (int i = 0; i < 2; ++i) {
            int idx = tid + 256 * i;
            int r = idx >> 2, c8 = (idx & 3) * 8;
            *(uint4*)&As[r * 32 + c8] = *(const uint4*)&A[(size_t)(m0 + r) * K + kt + c8];
            *(uint4*)&Bs[r * 32 + c8] = *(const uint4*)&Bt[(size_t)(n0 + r) * K + kt + c8];
        }
        __syncthreads();
        bf16x8 af[4], bfr[4];
#pragma unroll
        for (int t = 0; t < 4; ++t) {
            af[t]  = *(const bf16x8*)&As[(wm + t * 16 + m15) * 32 + q8];
            bfr[t] = *(const bf16x8*)&Bs[(wn + t * 16 + m15) * 32 + q8];
        }
#pragma unroll
        for (int i = 0; i < 4; ++i)
#pragma unroll
            for (int j = 0; j < 4; ++j)
                acc[i][j] = __builtin_amdgcn_mfma_f32_16x16x32_bf16(af[i], bfr[j], acc[i][j], 0, 0, 0);
    }
#pragma unroll
    for (int i = 0; i < 4; ++i)
#pragma unroll
        for (int j = 0; j < 4; ++j)
#pragma unroll
            for (int r = 0; r < 4; ++r)
                C[(size_t)(m0 + wm + i * 16 + (lane >> 4) * 4 + r) * N + n0 + wn + j * 16 + m15] = acc[i][j][r];
}

// ---------------------------------------------------------------------------
// Fused RoPE + bf16 cast. q fp32 [L][2048] -> q_bf (scaled by 0.125, exact
// exponent shift, folds the 1/sqrt(64) softmax scale into Q).
// k half of kv fp32 [L][1024] -> k_bf [L][512]. V untouched here.
// ---------------------------------------------------------------------------
__global__ void rope_cast_kernel(const float* __restrict__ q_ws, const float* __restrict__ kv_ws,
                                 const float* __restrict__ cosb, const float* __restrict__ sinb,
                                 u16* __restrict__ q_bf, u16* __restrict__ k_bf)
{
    int idx = blockIdx.x * 256 + threadIdx.x;
    const int TQ = L * NH * (HD / 2);
    const int TK = L * NKV * (HD / 2);
    if (idx < TQ) {
        int i = idx & 31, hh = (idx >> 5) & (NH - 1), row = idx >> 10;
        const float* p = q_ws + (size_t)row * 2048 + hh * 64 + 2 * i;
        float cc = cosb[row * 32 + i], ss = sinb[row * 32 + i];
        float xr = p[0], xi = p[1];
        u16* o = q_bf + (size_t)row * 2048 + hh * 64 + 2 * i;
        o[0] = f2bf((xr * cc - xi * ss) * 0.125f);
        o[1] = f2bf((xr * ss + xi * cc) * 0.125f);
    } else if (idx < TQ + TK) {
        int j = idx - TQ;
        int i = j & 31, hh = (j >> 5) & (NKV - 1), row = j >> 8;
        const float* p = kv_ws + (size_t)row * 1024 + hh * 64 + 2 * i;
        float cc = cosb[row * 32 + i], ss = sinb[row * 32 + i];
        float xr = p[0], xi = p[1];
        u16* o = k_bf + (size_t)row * 512 + hh * 64 + 2 * i;
        o[0] = f2bf(xr * cc - xi * ss);
        o[1] = f2bf(xr * ss + xi * cc);
    }
}

// ---------------------------------------------------------------------------
// MFMA flash attention (causal, GQA). Block = (head, 64 q-rows), 4 waves x
// 16 q-rows. Per 64-key chunk: K [key][d] and V^T [d][key] staged in LDS
// (stride 72 bf16 -> 2-way bank aliasing = free). Q A-frags persistent in
// registers (pre-scaled 0.125). S = QK^T via 8 MFMA; causal mask only on
// diagonal chunk; online softmax with 16-lane shfl_xor row reductions;
// P goes C-layout -> A-layout through per-wave LDS (same-wave, no barrier);
// O += P V^T via 8 MFMA, fp32 accumulators.
// ---------------------------------------------------------------------------
#define ATT_LDK 72
#define ATT_LDP 68

__global__ __launch_bounds__(256) void attn_mfma_kernel(
    const u16* __restrict__ qb,   // [L][NH*HD] bf16, pre-scaled
    const u16* __restrict__ kb,   // [L][NKV*HD] bf16 (rope'd)
    const u16* __restrict__ vt,   // [NKV*HD][L] bf16 (V transposed)
    u16* __restrict__ ob)         // [L][NH*HD] bf16
{
    __shared__ __align__(16) u16 Ks[64 * ATT_LDK];
    __shared__ __align__(16) u16 Vs[64 * ATT_LDK];
    __shared__ float Ps[4][16 * ATT_LDP];

    const int h = blockIdx.x;
    const int tile = (int)gridDim.y - 1 - (int)blockIdx.y;  // big tiles dispatch first
    const int gkv = h >> 2;
    const int tid = threadIdx.x;
    const int w = tid >> 6, lane = tid & 63;
    const int l15 = lane & 15, quad = lane >> 4;
    const int q0 = tile * 64 + w * 16;

    // persistent Q A-fragments: kd=0 -> d 0..31, kd=1 -> d 32..63
    bf16x8 qa[2];
    {
        const u16* qrow = qb + (size_t)(q0 + l15) * (NH * HD) + h * HD + quad * 8;
        qa[0] = *(const bf16x8*)(qrow);
        qa[1] = *(const bf16x8*)(qrow + 32);
    }
    f32x4 O[4];
#pragma unroll
    for (int i = 0; i < 4; ++i) O[i] = (f32x4){0.f, 0.f, 0.f, 0.f};
    float m_run[4], l_run[4];
#pragma unroll
    for (int r = 0; r < 4; ++r) { m_run[r] = -1e30f; l_run[r] = 0.f; }

    for (int c = 0; c <= tile; ++c) {
        const int key0 = c * 64;
        __syncthreads();   // Ks/Vs reuse safe
#pragma unroll
        for (int i = 0; i < 2; ++i) {
            int slot = tid + 256 * i;          // 0..511
            int r = slot >> 3, o8 = (slot & 7) * 8;
            *(uint4*)&Ks[r * ATT_LDK + o8] = *(const uint4*)&kb[(size_t)(key0 + r) * (NKV * HD) + gkv * HD + o8];
            *(uint4*)&Vs[r * ATT_LDK + o8] = *(const uint4*)&vt[(size_t)(gkv * HD + r) * L + key0 + o8];
        }
        __syncthreads();

        // S = Q K^T : 4 key-tiles x (2 kd)
        f32x4 S[4];
#pragma unroll
        for (int kt = 0; kt < 4; ++kt) {
            bf16x8 b0 = *(const bf16x8*)&Ks[(kt * 16 + l15) * ATT_LDK + quad * 8];
            bf16x8 b1 = *(const bf16x8*)&Ks[(kt * 16 + l15) * ATT_LDK + 32 + quad * 8];
            f32x4 s = (f32x4){0.f, 0.f, 0.f, 0.f};
            s = __builtin_amdgcn_mfma_f32_16x16x32_bf16(qa[0], b0, s, 0, 0, 0);
            s = __builtin_amdgcn_mfma_f32_16x16x32_bf16(qa[1], b1, s, 0, 0, 0);
            S[kt] = s;
        }
        if (c == tile) {   // diagonal chunk: mask key > row (local coords)
#pragma unroll
            for (int kt = 0; kt < 4; ++kt) {
                int keyl = kt * 16 + l15;
#pragma unroll
                for (int r = 0; r < 4; ++r)
                    if (keyl > w * 16 + quad * 4 + r) S[kt][r] = -1e30f;
            }
        }
        // online softmax per row (rows = quad*4+r, spread over 16 lanes)
        float alpha[4];
#pragma unroll
        for (int r = 0; r < 4; ++r) {
            float mx = fmaxf(fmaxf(S[0][r], S[1][r]), fmaxf(S[2][r], S[3][r]));
#pragma unroll
            for (int off = 1; off < 16; off <<= 1) mx = fmaxf(mx, __shfl_xor(mx, off));
            float mn = fmaxf(m_run[r], mx);
            alpha[r] = __expf(m_run[r] - mn);
            m_run[r] = mn;
            float rs = 0.f;
#pragma unroll
            for (int kt = 0; kt < 4; ++kt) { S[kt][r] = __expf(S[kt][r] - mn); rs += S[kt][r]; }
#pragma unroll
            for (int off = 1; off < 16; off <<= 1) rs += __shfl_xor(rs, off);
            l_run[r] = l_run[r] * alpha[r] + rs;
        }
        // P: C-layout -> A-layout via per-wave LDS (same-wave RAW, lgkmcnt only)
        float* pw = Ps[w];
#pragma unroll
        for (int kt = 0; kt < 4; ++kt)
#pragma unroll
            for (int r = 0; r < 4; ++r)
                pw[(quad * 4 + r) * ATT_LDP + kt * 16 + l15] = S[kt][r];
        bf16x8 pa[2];
#pragma unroll
        for (int kd = 0; kd < 2; ++kd) {
            const float* src = &pw[l15 * ATT_LDP + kd * 32 + quad * 8];
            bf16x8 t;
#pragma unroll
            for (int j = 0; j < 8; ++j) t[j] = (short)f2bf(src[j]);
            pa[kd] = t;
        }
        // O = O*alpha + P V
#pragma unroll
        for (int dt = 0; dt < 4; ++dt)
#pragma unroll
            for (int r = 0; r < 4; ++r) O[dt][r] *= alpha[r];
#pragma unroll
        for (int dt = 0; dt < 4; ++dt) {
            bf16x8 b0 = *(const bf16x8*)&Vs[(dt * 16 + l15) * ATT_LDK + quad * 8];
            bf16x8 b1 = *(const bf16x8*)&Vs[(dt * 16 + l15) * ATT_LDK + 32 + quad * 8];
            O[dt] = __builtin_amdgcn_mfma_f32_16x16x32_bf16(pa[0], b0, O[dt], 0, 0, 0);
            O[dt] = __builtin_amdgcn_mfma_f32_16x16x32_bf16(pa[1], b1, O[dt], 0, 0, 0);
        }
    }
#pragma unroll
    for (int r = 0; r < 4; ++r) {
        float inv = 1.0f / l_run[r];
        u16* orow = ob + (size_t)(q0 + quad * 4 + r) * (NH * HD) + h * HD;
#pragma unroll
        for (int dt = 0; dt < 4; ++dt)
            orow[dt * 16 + l15] = f2bf(O[dt][r] * inv);
    }
}

// ---------------------------------------------------------------------------
extern "C" void kernel_launch(void* const* d_in, const int* in_sizes, int n_in,
                              void* d_out, int out_size, void* d_ws, size_t ws_size,
                              hipStream_t stream)
{
    const float* x  = (const float*)d_in[0];
    const float* wq = (const float*)d_in[1];
    const float* wk = (const float*)d_in[2];
    const float* wv = (const float*)d_in[3];
    const float* wo = (const float*)d_in[4];
    const float* fc = (const float*)d_in[5];
    const float* fs = (const float*)d_in[6];
    // d_in[7] = mask: unused (hard causal mask == -1e9 additive path in fp32)
    float* out = (float*)d_out;

    // Workspace 52 MB with aliasing (lifetimes are stream-ordered):
    // xb 8MB | wqT 8MB | wkvT 4MB | woT 8MB | q_ws 16MB | kv_ws 8MB
    // q_bf aliases wqT (dead after GEMMs); k_bf/v_t alias wkvT; ab aliases xb.
    u16*   xb    = (u16*)d_ws;
    u16*   wqT   = xb   + (size_t)2048 * 2048;
    u16*   wkvT  = wqT  + (size_t)2048 * 2048;
    u16*   woT   = wkvT + (size_t)1024 * 2048;
    float* q_ws  = (float*)(woT + (size_t)2048 * 2048);
    float* kv_ws = q_ws + (size_t)2048 * 2048;
    u16*   q_bf  = wqT;
    u16*   k_bf  = wkvT;
    u16*   v_t   = wkvT + (size_t)512 * 2048;
    u16*   ab    = xb;

    cast_x_kernel<<<4096, 256, 0, stream>>>(x, xb, (2048 * 2048) / 4);
    cast_transpose_kernel<<<dim3(64, 64), 256, 0, stream>>>(wq, wqT, 2048, 2048);
    cast_transpose_kernel<<<dim3(16, 64), 256, 0, stream>>>(wk, wkvT, 512, 2048);
    cast_transpose_kernel<<<dim3(16, 64), 256, 0, stream>>>(wv, wkvT + (size_t)512 * 2048, 512, 2048);
    cast_transpose_kernel<<<dim3(64, 64), 256, 0, stream>>>(wo, woT, 2048, 2048);

    gemm_mfma_kernel<<<dim3(16, 16), 256, 0, stream>>>(xb, wqT, q_ws, 2048, 2048, 2048);
    gemm_mfma_kernel<<<dim3(8, 16), 256, 0, stream>>>(xb, wkvT, kv_ws, 2048, 1024, 2048);

    const int total_pairs = L * NH * (HD / 2) + L * NKV * (HD / 2);
    rope_cast_kernel<<<(total_pairs + 255) / 256, 256, 0, stream>>>(q_ws, kv_ws, fc, fs, q_bf, k_bf);

    // V^T: kv_ws cols 512..1023 (fp32, ldi=1024) -> v_t bf16 [512][2048]
    cast_transpose_kernel<<<dim3(16, 64), 256, 0, stream>>>(kv_ws + 512, v_t, 1024, 2048);

    attn_mfma_kernel<<<dim3(NH, L / 64), 256, 0, stream>>>(q_bf, k_bf, v_t, ab);

    gemm_mfma_kernel<<<dim3(16, 16), 256, 0, stream>>>(ab, woT, out, 2048, 2048, 2048);
}

// Round 5
// 318.113 us; speedup vs baseline: 9.5891x; 1.0881x over previous
//
#include <hip/hip_runtime.h>
#include <hip/hip_bf16.h>

#define L 2048
#define D 2048
#define NH 32
#define NKV 8
#define HD 64

typedef unsigned short u16;
typedef __attribute__((ext_vector_type(8))) short bf16x8;   // 8 bf16 in 4 VGPRs
typedef __attribute__((ext_vector_type(4))) float f32x4;

#define QSCALE 0.1803368801f   // 0.125 * log2(e): S comes out in log2 domain

__device__ __forceinline__ u16 f2bf(float x) {
    __hip_bfloat16 b = __float2bfloat16(x);
    return *reinterpret_cast<u16*>(&b);
}

// Async global->LDS, 16B per lane. HW semantics: wave-uniform base (first
// lane's ptr) + lane*16; our layouts are lane-order contiguous to match.
__device__ __forceinline__ void gload_lds16(const void* g, void* l) {
    __builtin_amdgcn_global_load_lds(
        (const __attribute__((address_space(1))) unsigned int*)g,
        (__attribute__((address_space(3))) unsigned int*)l, 16, 0, 0);
}

// ---------------------------------------------------------------------------
// x fp32 -> bf16, float4-vectorized.
// ---------------------------------------------------------------------------
__global__ void cast_x_kernel(const float* __restrict__ in, u16* __restrict__ out, int n4)
{
    int i = blockIdx.x * 256 + threadIdx.x;
    if (i < n4) {
        float4 v = ((const float4*)in)[i];
        ushort4 o;
        o.x = f2bf(v.x); o.y = f2bf(v.y); o.z = f2bf(v.z); o.w = f2bf(v.w);
        ((ushort4*)out)[i] = o;
    }
}

// ---------------------------------------------------------------------------
// All 4 weight transposes (fp32 [2048][C] -> bf16 [C][2048]) in one dispatch;
// blockIdx.z selects the job. wq/wk/wv land stacked in wqkvT [3072][2048].
// ---------------------------------------------------------------------------
__global__ __launch_bounds__(256) void wtrans_kernel(
    const float* __restrict__ wq, const float* __restrict__ wk,
    const float* __restrict__ wv, const float* __restrict__ wo,
    u16* __restrict__ wqkvT, u16* __restrict__ woT)
{
    const int z = blockIdx.z;
    const float* src; u16* dst; int C;
    if (z == 0)      { src = wq; dst = wqkvT;                           C = 2048; }
    else if (z == 1) { src = wk; dst = wqkvT + (size_t)2048 * 2048;     C = 512;  }
    else if (z == 2) { src = wv; dst = wqkvT + (size_t)2560 * 2048;     C = 512;  }
    else             { src = wo; dst = woT;                             C = 2048; }
    const int c0 = blockIdx.x * 32;
    if (c0 >= C) return;
    const int r0 = blockIdx.y * 32;
    __shared__ float tile[32][33];
    const int tx = threadIdx.x & 31, ty = threadIdx.x >> 5;
#pragma unroll
    for (int i = 0; i < 32; i += 8)
        tile[ty + i][tx] = src[(size_t)(r0 + ty + i) * C + c0 + tx];
    __syncthreads();
#pragma unroll
    for (int i = 0; i < 32; i += 8)
        dst[(size_t)(c0 + ty + i) * 2048 + r0 + tx] = f2bf(tile[tx][ty + i]);
}

// ---------------------------------------------------------------------------
// Single-wave double-buffered MFMA GEMM. Block = 64 threads = 1 wave owning a
// 64x64 C-tile (4x4 mfma_f32_16x16x32_bf16), BK=32. Staging via
// global_load_lds dwordx4 into LDS buf (k+1) while computing buf k; no
// __syncthreads at all (1 wave) -> the fine-grained s_waitcnt vmcnt(8) is the
// only wait. Buffer reuse is safe: every ds_read of iter i feeds an MFMA in
// iter i (register dependency forces lgkm completion) before iter i+1 issues
// DMA into that buffer.
// MODE 0: C fp32 [M][N].
// MODE 1: fused epilogue -> bf16 qkv [2048][3072]; cols<2560 get RoPE (pairs
//         are lane-adjacent: shfl_xor(v,1)); cols<2048 (Q) also scaled by
//         0.125*log2e so attention works in exp2 domain.
// ---------------------------------------------------------------------------
template <int MODE>
__global__ __launch_bounds__(64) void gemm1w_kernel(
    const u16* __restrict__ A, const u16* __restrict__ Bt, void* __restrict__ Cout,
    int N, int K, const float* __restrict__ fc, const float* __restrict__ fs)
{
    __shared__ __align__(16) u16 As[2][64 * 32];
    __shared__ __align__(16) u16 Bs[2][64 * 32];
    const int lane = threadIdx.x;
    const int m0 = blockIdx.y * 64, n0 = blockIdx.x * 64;
    const int l15 = lane & 15, quad = lane >> 4, q8 = quad * 8;
    const int sr = lane >> 2, sc = (lane & 3) * 8;      // staging: 4 lanes/row

    const u16* pa = A  + (size_t)(m0 + sr) * K + sc;
    const u16* pb = Bt + (size_t)(n0 + sr) * K + sc;

    f32x4 acc[4][4];
#pragma unroll
    for (int i = 0; i < 4; ++i)
#pragma unroll
        for (int j = 0; j < 4; ++j) acc[i][j] = (f32x4){0.f, 0.f, 0.f, 0.f};

    const int nIter = K / 32;
#pragma unroll
    for (int a = 0; a < 4; ++a) {                        // prologue: buf 0
        gload_lds16(pa + a * 16 * K, &As[0][(a * 16 + sr) * 32 + sc]);
        gload_lds16(pb + a * 16 * K, &Bs[0][(a * 16 + sr) * 32 + sc]);
    }
    for (int it = 0; it < nIter; ++it) {
        const int ktn = (it + 1 < nIter) ? (it + 1) * 32 : 0;  // wrap: dummy prefetch
        const int nb = (it + 1) & 1, cb = it & 1;
#pragma unroll
        for (int a = 0; a < 4; ++a) {
            gload_lds16(pa + (size_t)a * 16 * K + ktn, &As[nb][(a * 16 + sr) * 32 + sc]);
            gload_lds16(pb + (size_t)a * 16 * K + ktn, &Bs[nb][(a * 16 + sr) * 32 + sc]);
        }
        asm volatile("s_waitcnt vmcnt(8)" ::: "memory");   // current buf's 8 DMAs done
        bf16x8 af[4], bfr[4];
#pragma unroll
        for (int t = 0; t < 4; ++t) {
            af[t]  = *(const bf16x8*)&As[cb][(t * 16 + l15) * 32 + q8];
            bfr[t] = *(const bf16x8*)&Bs[cb][(t * 16 + l15) * 32 + q8];
        }
#pragma unroll
        for (int i = 0; i < 4; ++i)
#pragma unroll
            for (int j = 0; j < 4; ++j)
                acc[i][j] = __builtin_amdgcn_mfma_f32_16x16x32_bf16(af[i], bfr[j], acc[i][j], 0, 0, 0);
    }

    if (MODE == 0) {
        float* C = (float*)Cout;
#pragma unroll
        for (int i = 0; i < 4; ++i)
#pragma unroll
            for (int j = 0; j < 4; ++j)
#pragma unroll
                for (int r = 0; r < 4; ++r)
                    C[(size_t)(m0 + i * 16 + quad * 4 + r) * N + n0 + j * 16 + l15] = acc[i][j][r];
    } else {
        u16* O = (u16*)Cout;
        const bool do_rope = (n0 < 2560);                 // q & k regions
        const float scl = (n0 < 2048) ? QSCALE : 1.0f;    // q only
        const int odd = l15 & 1;
#pragma unroll
        for (int i = 0; i < 4; ++i)
#pragma unroll
            for (int j = 0; j < 4; ++j)
#pragma unroll
                for (int r = 0; r < 4; ++r) {
                    const int row = m0 + i * 16 + quad * 4 + r;
                    const int col = n0 + j * 16 + l15;
                    float v = acc[i][j][r], o;
                    if (do_rope) {
                        const int i2 = (j * 16 + l15) >> 1;   // head-dim pair (64-aligned tiles)
                        const float c = fc[row * 32 + i2], s = fs[row * 32 + i2];
                        const float p = __shfl_xor(v, 1);
                        o = (odd ? (p * s + v * c) : (v * c - p * s)) * scl;
                    } else {
                        o = v;                                // V: plain cast
                    }
                    O[(size_t)row * 3072 + col] = f2bf(o);
                }
    }
}

// ---------------------------------------------------------------------------
// V columns of qkv (bf16 [2048][3072], cols 2560..3071) -> vt bf16 [512][2048].
// ---------------------------------------------------------------------------
__global__ __launch_bounds__(256) void vtrans_kernel(
    const u16* __restrict__ qkv, u16* __restrict__ vt)
{
    __shared__ u16 tile[32][34];
    const int tx = threadIdx.x & 31, ty = threadIdx.x >> 5;
    const int r0 = blockIdx.y * 32, c0 = blockIdx.x * 32;
#pragma unroll
    for (int i = 0; i < 32; i += 8)
        tile[ty + i][tx] = qkv[(size_t)(r0 + ty + i) * 3072 + 2560 + c0 + tx];
    __syncthreads();
#pragma unroll
    for (int i = 0; i < 32; i += 8)
        vt[(size_t)(c0 + ty + i) * 2048 + r0 + tx] = tile[tx][ty + i];
}

// ---------------------------------------------------------------------------
// MFMA flash attention (causal, GQA), exp2 domain (Q pre-scaled by
// 0.125*log2e in the GEMM epilogue). Block = (head, 64 q-rows), 4 waves x 16
// rows. P repack C->A layout through per-wave bf16 LDS (16 b16 writes, 2
// conflict-free b128 reads). Row-sums via MFMA against a ones-fragment.
// ---------------------------------------------------------------------------
#define ATT_LDK 72     // u16 stride for K/V tiles (144B rows, 16B-aligned)
#define ATT_LDP 72     // u16 stride for P repack

__global__ __launch_bounds__(256) void attn_mfma_kernel(
    const u16* __restrict__ qkv,  // [2048][3072] bf16: q|k|v
    const u16* __restrict__ vt,   // [512][2048] bf16 (V^T)
    u16* __restrict__ ob)         // [2048][2048] bf16
{
    __shared__ __align__(16) u16 Ks[64 * ATT_LDK];
    __shared__ __align__(16) u16 Vs[64 * ATT_LDK];
    __shared__ __align__(16) u16 Ps[4][16 * ATT_LDP];

    const int h = blockIdx.x;
    const int tile = (int)gridDim.y - 1 - (int)blockIdx.y;  // big tiles first
    const int gkv = h >> 2;
    const int tid = threadIdx.x;
    const int w = tid >> 6, lane = tid & 63;
    const int l15 = lane & 15, quad = lane >> 4;
    const int q0 = tile * 64 + w * 16;

    bf16x8 ones;
#pragma unroll
    for (int j = 0; j < 8; ++j) ones[j] = (short)0x3F80;   // bf16 1.0

    bf16x8 qa[2];
    {
        const u16* qrow = qkv + (size_t)(q0 + l15) * 3072 + h * HD + quad * 8;
        qa[0] = *(const bf16x8*)(qrow);
        qa[1] = *(const bf16x8*)(qrow + 32);
    }
    f32x4 O[4];
#pragma unroll
    for (int i = 0; i < 4; ++i) O[i] = (f32x4){0.f, 0.f, 0.f, 0.f};
    float m_run[4], l_run[4];
#pragma unroll
    for (int r = 0; r < 4; ++r) { m_run[r] = -1e30f; l_run[r] = 0.f; }

    for (int c = 0; c <= tile; ++c) {
        const int key0 = c * 64;
        __syncthreads();
#pragma unroll
        for (int i = 0; i < 2; ++i) {
            int slot = tid + 256 * i;               // 0..511: 64 rows x 8 chunks
            int r = slot >> 3, o8 = (slot & 7) * 8;
            *(uint4*)&Ks[r * ATT_LDK + o8] =
                *(const uint4*)&qkv[(size_t)(key0 + r) * 3072 + 2048 + gkv * HD + o8];
            *(uint4*)&Vs[r * ATT_LDK + o8] =
                *(const uint4*)&vt[(size_t)(gkv * HD + r) * 2048 + key0 + o8];
        }
        __syncthreads();

        // S = Q K^T (log2 domain)
        f32x4 S[4];
#pragma unroll
        for (int kt = 0; kt < 4; ++kt) {
            bf16x8 b0 = *(const bf16x8*)&Ks[(kt * 16 + l15) * ATT_LDK + quad * 8];
            bf16x8 b1 = *(const bf16x8*)&Ks[(kt * 16 + l15) * ATT_LDK + 32 + quad * 8];
            f32x4 s = (f32x4){0.f, 0.f, 0.f, 0.f};
            s = __builtin_amdgcn_mfma_f32_16x16x32_bf16(qa[0], b0, s, 0, 0, 0);
            s = __builtin_amdgcn_mfma_f32_16x16x32_bf16(qa[1], b1, s, 0, 0, 0);
            S[kt] = s;
        }
        if (c == tile) {   // diagonal chunk causal mask (local coords)
#pragma unroll
            for (int kt = 0; kt < 4; ++kt) {
                int keyl = kt * 16 + l15;
#pragma unroll
                for (int r = 0; r < 4; ++r)
                    if (keyl > w * 16 + quad * 4 + r) S[kt][r] = -1e30f;
            }
        }
        // online softmax: max over row (16 lanes), exp2, alpha
        float alpha[4];
#pragma unroll
        for (int r = 0; r < 4; ++r) {
            float mx = fmaxf(fmaxf(S[0][r], S[1][r]), fmaxf(S[2][r], S[3][r]));
#pragma unroll
            for (int off = 1; off < 16; off <<= 1) mx = fmaxf(mx, __shfl_xor(mx, off));
            float mn = fmaxf(m_run[r], mx);
            alpha[r] = exp2f(m_run[r] - mn);
            m_run[r] = mn;
#pragma unroll
            for (int kt = 0; kt < 4; ++kt) S[kt][r] = exp2f(S[kt][r] - mn);
        }
        // P repack: C-layout -> A-layout, bf16 in LDS (same-wave, lgkm only)
        u16* pw = Ps[w];
#pragma unroll
        for (int kt = 0; kt < 4; ++kt)
#pragma unroll
            for (int r = 0; r < 4; ++r)
                pw[(quad * 4 + r) * ATT_LDP + kt * 16 + l15] = f2bf(S[kt][r]);
        bf16x8 pa0 = *(const bf16x8*)&pw[l15 * ATT_LDP + quad * 8];
        bf16x8 pa1 = *(const bf16x8*)&pw[l15 * ATT_LDP + 32 + quad * 8];

        // row-sums via MFMA with ones-B (replicated across l15 like m/l)
        f32x4 rs = (f32x4){0.f, 0.f, 0.f, 0.f};
        rs = __builtin_amdgcn_mfma_f32_16x16x32_bf16(pa0, ones, rs, 0, 0, 0);
        rs = __builtin_amdgcn_mfma_f32_16x16x32_bf16(pa1, ones, rs, 0, 0, 0);
#pragma unroll
        for (int r = 0; r < 4; ++r) l_run[r] = l_run[r] * alpha[r] + rs[r];

        // O = O*alpha + P V
#pragma unroll
        for (int dt = 0; dt < 4; ++dt)
#pragma unroll
            for (int r = 0; r < 4; ++r) O[dt][r] *= alpha[r];
#pragma unroll
        for (int dt = 0; dt < 4; ++dt) {
            bf16x8 b0 = *(const bf16x8*)&Vs[(dt * 16 + l15) * ATT_LDK + quad * 8];
            bf16x8 b1 = *(const bf16x8*)&Vs[(dt * 16 + l15) * ATT_LDK + 32 + quad * 8];
            O[dt] = __builtin_amdgcn_mfma_f32_16x16x32_bf16(pa0, b0, O[dt], 0, 0, 0);
            O[dt] = __builtin_amdgcn_mfma_f32_16x16x32_bf16(pa1, b1, O[dt], 0, 0, 0);
        }
    }
#pragma unroll
    for (int r = 0; r < 4; ++r) {
        float inv = 1.0f / l_run[r];
        u16* orow = ob + (size_t)(q0 + quad * 4 + r) * 2048 + h * HD;
#pragma unroll
        for (int dt = 0; dt < 4; ++dt)
            orow[dt * 16 + l15] = f2bf(O[dt][r] * inv);
    }
}

// ---------------------------------------------------------------------------
extern "C" void kernel_launch(void* const* d_in, const int* in_sizes, int n_in,
                              void* d_out, int out_size, void* d_ws, size_t ws_size,
                              hipStream_t stream)
{
    const float* x  = (const float*)d_in[0];
    const float* wq = (const float*)d_in[1];
    const float* wk = (const float*)d_in[2];
    const float* wv = (const float*)d_in[3];
    const float* wo = (const float*)d_in[4];
    const float* fc = (const float*)d_in[5];
    const float* fs = (const float*)d_in[6];
    // d_in[7] = mask: unused (hard causal == -1e9 additive path in fp32)
    float* out = (float*)d_out;

    // Workspace 50 MB:
    // xb 8MB | wqkvT 12MB | woT 8MB | qkv_bf 12MB | vt 2MB | ab 8MB
    u16* xb     = (u16*)d_ws;
    u16* wqkvT  = xb     + (size_t)2048 * 2048;
    u16* woT    = wqkvT  + (size_t)3072 * 2048;
    u16* qkv_bf = woT    + (size_t)2048 * 2048;
    u16* vt     = qkv_bf + (size_t)2048 * 3072;
    u16* ab     = vt     + (size_t)512 * 2048;

    cast_x_kernel<<<4096, 256, 0, stream>>>(x, xb, (2048 * 2048) / 4);
    wtrans_kernel<<<dim3(64, 64, 4), 256, 0, stream>>>(wq, wk, wv, wo, wqkvT, woT);

    // QKV projection + fused RoPE/scale/bf16 epilogue: [2048][3072]
    gemm1w_kernel<1><<<dim3(3072 / 64, 2048 / 64), 64, 0, stream>>>(
        xb, wqkvT, qkv_bf, 3072, 2048, fc, fs);

    vtrans_kernel<<<dim3(16, 64), 256, 0, stream>>>(qkv_bf, vt);

    attn_mfma_kernel<<<dim3(NH, L / 64), 256, 0, stream>>>(qkv_bf, vt, ab);

    // out projection -> fp32 output
    gemm1w_kernel<0><<<dim3(2048 / 64, 2048 / 64), 64, 0, stream>>>(
        ab, woT, out, 2048, 2048, nullptr, nullptr);
}